// Round 1
// baseline (300.838 us; speedup 1.0000x reference)
//
#include <hip/hip_runtime.h>

// B=4, S=1024, E=1024, H=16, D=64. All GEMMs are 4096x1024x1024 (A MxK row-major,
// W NxK row-major => C = A * W^T + bias).

typedef _Float16 v8h __attribute__((ext_vector_type(8)));
typedef _Float16 v4h __attribute__((ext_vector_type(4)));
typedef float    v4f __attribute__((ext_vector_type(4)));

#define MFMA_F16(A_, B_, C_) __builtin_amdgcn_mfma_f32_16x16x32_f16(A_, B_, C_, 0, 0, 0)

// ---------------- fp32 -> fp16 conversion (5 tensors, one launch) ----------------
__global__ __launch_bounds__(256) void cvt5_kernel(
    const float* __restrict__ s0, const float* __restrict__ s1,
    const float* __restrict__ s2, const float* __restrict__ s3,
    const float* __restrict__ s4,
    _Float16* __restrict__ d0, _Float16* __restrict__ d1,
    _Float16* __restrict__ d2, _Float16* __restrict__ d3,
    _Float16* __restrict__ d4,
    int n0, int n1, int n2, int n3, int n4)
{
    const float* s; _Float16* d; int n;
    switch (blockIdx.y) {
        case 0:  s = s0; d = d0; n = n0; break;
        case 1:  s = s1; d = d1; n = n1; break;
        case 2:  s = s2; d = d2; n = n2; break;
        case 3:  s = s3; d = d3; n = n3; break;
        default: s = s4; d = d4; n = n4; break;
    }
    int i = (blockIdx.x * 256 + threadIdx.x) * 4;
    if (i >= n) return;
    float4 f = *(const float4*)(s + i);
    v4h o = { (_Float16)f.x, (_Float16)f.y, (_Float16)f.z, (_Float16)f.w };
    *(v4h*)(d + i) = o;
}

// ---------------- shared GEMM core: C = A * W^T + bias ----------------
// 128x128 tile, BK=64, 256 threads (4 waves, 2x2), each wave 64x64 via 4x4 MFMA tiles.
// mode 0: write fp16 to (B,H,S,D);  mode 1: write fp16 transposed to (B,H,D,S);
// mode 2: write fp32 row-major (M,N).
__device__ __forceinline__ void gemm_core(const _Float16* __restrict__ A,
                                          const _Float16* __restrict__ W,
                                          const float* __restrict__ bias,
                                          int mode, void* __restrict__ outp)
{
    __shared__ __align__(16) _Float16 As[128 * 72];  // +8 pad breaks bank conflicts
    __shared__ __align__(16) _Float16 Bs[128 * 72];

    const int tid  = threadIdx.x;
    const int wave = tid >> 6, lane = tid & 63;
    const int quad = lane >> 4, n16 = lane & 15;
    const int wm = wave >> 1, wn = wave & 1;
    const int row0 = blockIdx.y * 128, col0 = blockIdx.x * 128;
    const int sr = tid >> 3, scn = tid & 7;   // staging: 32 rows x 8 chunks of 8 halves

    v4f acc[4][4] = {};

    for (int kb = 0; kb < 1024; kb += 64) {
        __syncthreads();
        #pragma unroll
        for (int p = 0; p < 4; p++) {
            int rr = p * 32 + sr;
            *(v8h*)(&As[rr * 72 + scn * 8]) =
                *(const v8h*)(A + (size_t)(row0 + rr) * 1024 + kb + scn * 8);
            *(v8h*)(&Bs[rr * 72 + scn * 8]) =
                *(const v8h*)(W + (size_t)(col0 + rr) * 1024 + kb + scn * 8);
        }
        __syncthreads();
        #pragma unroll
        for (int ks = 0; ks < 64; ks += 32) {
            v8h af[4], bf[4];
            #pragma unroll
            for (int i = 0; i < 4; i++)
                af[i] = *(const v8h*)(&As[(wm * 64 + i * 16 + n16) * 72 + ks + quad * 8]);
            #pragma unroll
            for (int j = 0; j < 4; j++)
                bf[j] = *(const v8h*)(&Bs[(wn * 64 + j * 16 + n16) * 72 + ks + quad * 8]);
            #pragma unroll
            for (int i = 0; i < 4; i++)
                #pragma unroll
                for (int j = 0; j < 4; j++)
                    acc[i][j] = MFMA_F16(af[i], bf[j], acc[i][j]);
        }
    }

    // C/D layout (verified gfx950): col = lane&15, row = (lane>>4)*4 + reg
    #pragma unroll
    for (int i = 0; i < 4; i++)
        #pragma unroll
        for (int j = 0; j < 4; j++)
            #pragma unroll
            for (int r = 0; r < 4; r++) {
                int row = row0 + wm * 64 + i * 16 + quad * 4 + r;
                int col = col0 + wn * 64 + j * 16 + n16;
                float v = acc[i][j][r] + bias[col];
                if (mode == 0) {
                    int b = row >> 10, s = row & 1023, h = col >> 6, d = col & 63;
                    ((_Float16*)outp)[(((size_t)(b * 16 + h)) * 1024 + s) * 64 + d] = (_Float16)v;
                } else if (mode == 1) {
                    int b = row >> 10, s = row & 1023, h = col >> 6, d = col & 63;
                    ((_Float16*)outp)[(((size_t)(b * 16 + h)) * 64 + d) * 1024 + s] = (_Float16)v;
                } else {
                    ((float*)outp)[(size_t)row * 1024 + col] = v;
                }
            }
}

__global__ __launch_bounds__(256) void gemm_qv_kernel(
    const _Float16* __restrict__ Aq, const _Float16* __restrict__ Av,
    const _Float16* __restrict__ Wq, const _Float16* __restrict__ Wv,
    const float* __restrict__ bq, const float* __restrict__ bv,
    _Float16* __restrict__ q_out, _Float16* __restrict__ v_out)
{
    int z = blockIdx.z;
    const _Float16* A = z ? Av : Aq;
    const _Float16* W = z ? Wv : Wq;
    const float* bias = z ? bv : bq;
    void* outp = z ? (void*)v_out : (void*)q_out;
    gemm_core(A, W, bias, z ? 1 : 0, outp);
}

__global__ __launch_bounds__(256) void gemm_o_kernel(
    const _Float16* __restrict__ A, const _Float16* __restrict__ W,
    const float* __restrict__ bias, float* __restrict__ outp)
{
    gemm_core(A, W, bias, 2, (void*)outp);
}

// ---------------- fused attention (flash-style, K == Q) ----------------
// Block: 64 q-rows (4 waves x 16). grid = (S/64, B*H).
// scores[q,k] = (dot(q_q, q_k) + rq[bucket(q-k)]) / 8 ; softmax over k;
// out = attn @ V + Sum_t bucket_sum_t * rpv_table[t].
__global__ __launch_bounds__(256) void attn_kernel(
    const _Float16* __restrict__ qb,   // (B,H,S,D) fp16
    const _Float16* __restrict__ vt,   // (B,H,D,S) fp16 (transposed)
    const float* __restrict__ rpk, const float* __restrict__ rpv,  // (5,64) fp32
    _Float16* __restrict__ attn_o)     // (B*S, H*D) fp16
{
    const int bh = blockIdx.y;
    const int q0 = blockIdx.x * 64;
    const int tid = threadIdx.x;
    const int wave = tid >> 6, lane = tid & 63;
    const int quad = lane >> 4, n16 = lane & 15;
    const int qw = q0 + wave * 16;   // this wave's q-row base
    const _Float16* Qh = qb + (size_t)bh * 1024 * 64;
    const _Float16* Vh = vt + (size_t)bh * 64 * 1024;

    __shared__ __align__(16) _Float16 Ks[64 * 72];
    __shared__ __align__(16) _Float16 Vs[64 * 72];
    __shared__ __align__(16) _Float16 Ps[4][16 * 72];
    __shared__ float rqs[4][16][5];

    // ---- rq[m][t] = dot(q_row m, rpk_table[t]) ----
    {
        int m = lane >> 2, seg = lane & 3;
        const _Float16* qrow = Qh + (qw + m) * 64 + seg * 16;
        float qd[16];
        #pragma unroll
        for (int x = 0; x < 16; x++) qd[x] = (float)qrow[x];
        #pragma unroll
        for (int t = 0; t < 5; t++) {
            float s = 0.f;
            #pragma unroll
            for (int x = 0; x < 16; x++) s += qd[x] * rpk[t * 64 + seg * 16 + x];
            s += __shfl_xor(s, 1);
            s += __shfl_xor(s, 2);
            if (seg == 0) rqs[wave][m][t] = s;
        }
    }
    __syncthreads();

    float rqv[4][5];
    #pragma unroll
    for (int r = 0; r < 4; r++)
        #pragma unroll
        for (int t = 0; t < 5; t++)
            rqv[r][t] = rqs[wave][quad * 4 + r][t];

    // Q A-fragments: A[m=lane&15][k=quad*8+j]
    v8h aq0 = *(const v8h*)(Qh + (qw + n16) * 64 + quad * 8);
    v8h aq1 = *(const v8h*)(Qh + (qw + n16) * 64 + 32 + quad * 8);

    float mrow[4], lrow[4], blo[4], bm1[4], bc0[4], bp1[4];
    v4f O[4] = {};
    #pragma unroll
    for (int r = 0; r < 4; r++) {
        mrow[r] = -1e30f; lrow[r] = 0.f;
        blo[r] = 0.f; bm1[r] = 0.f; bc0[r] = 0.f; bp1[r] = 0.f;
    }

    const int sr = tid >> 3, scn = tid & 7;

    for (int kb = 0; kb < 1024; kb += 64) {
        __syncthreads();
        #pragma unroll
        for (int p = 0; p < 2; p++) {
            int rr = p * 32 + sr;
            *(v8h*)(&Ks[rr * 72 + scn * 8]) = *(const v8h*)(Qh + (size_t)(kb + rr) * 64 + scn * 8);
            *(v8h*)(&Vs[rr * 72 + scn * 8]) = *(const v8h*)(Vh + (size_t)rr * 1024 + kb + scn * 8);
        }
        __syncthreads();

        // ---- scores: 4 tiles of 16q x 16k ----
        float sc[4][4];
        #pragma unroll
        for (int t = 0; t < 4; t++) {
            v8h bk0 = *(const v8h*)(&Ks[(t * 16 + n16) * 72 + quad * 8]);
            v8h bk1 = *(const v8h*)(&Ks[(t * 16 + n16) * 72 + 32 + quad * 8]);
            v4f s = {0.f, 0.f, 0.f, 0.f};
            s = MFMA_F16(aq0, bk0, s);
            s = MFMA_F16(aq1, bk1, s);
            #pragma unroll
            for (int r = 0; r < 4; r++) {
                int diff = (qw + quad * 4 + r) - (kb + t * 16 + n16);
                float rv = diff >= 2  ? rqv[r][4]
                         : diff == 1  ? rqv[r][3]
                         : diff == 0  ? rqv[r][2]
                         : diff == -1 ? rqv[r][1]
                                      : rqv[r][0];
                sc[t][r] = (s[r] + rv) * 0.125f;
            }
        }

        // ---- online softmax (per-lane partials; only max needs cross-lane) ----
        float p4[4][4];
        #pragma unroll
        for (int r = 0; r < 4; r++) {
            float mx = fmaxf(fmaxf(sc[0][r], sc[1][r]), fmaxf(sc[2][r], sc[3][r]));
            mx = fmaxf(mx, __shfl_xor(mx, 1));
            mx = fmaxf(mx, __shfl_xor(mx, 2));
            mx = fmaxf(mx, __shfl_xor(mx, 4));
            mx = fmaxf(mx, __shfl_xor(mx, 8));
            float mnew  = fmaxf(mrow[r], mx);
            float alpha = __expf(mrow[r] - mnew);
            mrow[r] = mnew;
            float psum = 0.f, plo = 0.f, pm = 0.f, pc = 0.f, pp = 0.f;
            #pragma unroll
            for (int t = 0; t < 4; t++) {
                float p = __expf(sc[t][r] - mnew);
                p4[t][r] = p;
                psum += p;
                int diff = (qw + quad * 4 + r) - (kb + t * 16 + n16);
                if (diff >= 2)       plo += p;
                else if (diff == 1)  pm  += p;
                else if (diff == 0)  pc  += p;
                else if (diff == -1) pp  += p;
            }
            lrow[r] = lrow[r] * alpha + psum;
            blo[r]  = blo[r]  * alpha + plo;
            bm1[r]  = bm1[r]  * alpha + pm;
            bc0[r]  = bc0[r]  * alpha + pc;
            bp1[r]  = bp1[r]  * alpha + pp;
            #pragma unroll
            for (int dt = 0; dt < 4; dt++) O[dt][r] *= alpha;
        }

        // ---- P: C-layout -> LDS -> A-layout (same-wave DS ops are in-order) ----
        #pragma unroll
        for (int t = 0; t < 4; t++)
            #pragma unroll
            for (int r = 0; r < 4; r++)
                Ps[wave][(quad * 4 + r) * 72 + t * 16 + n16] = (_Float16)p4[t][r];

        v8h pf0 = *(const v8h*)(&Ps[wave][n16 * 72 + quad * 8]);
        v8h pf1 = *(const v8h*)(&Ps[wave][n16 * 72 + 32 + quad * 8]);
        #pragma unroll
        for (int dt = 0; dt < 4; dt++) {
            v8h v0 = *(const v8h*)(&Vs[(dt * 16 + n16) * 72 + quad * 8]);
            v8h v1 = *(const v8h*)(&Vs[(dt * 16 + n16) * 72 + 32 + quad * 8]);
            O[dt] = MFMA_F16(pf0, v0, O[dt]);
            O[dt] = MFMA_F16(pf1, v1, O[dt]);
        }
    }

    // ---- epilogue: reduce l + buckets across the 16 lanes, add rpv term ----
    #pragma unroll
    for (int r = 0; r < 4; r++) {
        float l = lrow[r], lo = blo[r], a1 = bm1[r], a0 = bc0[r], ap = bp1[r];
        #pragma unroll
        for (int off = 1; off < 16; off <<= 1) {
            l  += __shfl_xor(l,  off);
            lo += __shfl_xor(lo, off);
            a1 += __shfl_xor(a1, off);
            a0 += __shfl_xor(a0, off);
            ap += __shfl_xor(ap, off);
        }
        float hi  = l - lo - a1 - a0 - ap;  // k >= q+2 bucket
        float inv = 1.0f / l;
        int qg = qw + quad * 4 + r;
        int brow = (bh >> 4) * 1024 + qg;   // b*S + q
        int hcol = (bh & 15) * 64;          // h*D
        #pragma unroll
        for (int dt = 0; dt < 4; dt++) {
            int d = dt * 16 + n16;
            float w2 = lo * rpv[4 * 64 + d] + a1 * rpv[3 * 64 + d] + a0 * rpv[2 * 64 + d]
                     + ap * rpv[1 * 64 + d] + hi * rpv[0 * 64 + d];
            float val = (O[dt][r] + w2) * inv;
            attn_o[(size_t)brow * 1024 + hcol + d] = (_Float16)val;
        }
    }
}

// ---------------- host launcher ----------------
extern "C" void kernel_launch(void* const* d_in, const int* in_sizes, int n_in,
                              void* d_out, int out_size, void* d_ws, size_t ws_size,
                              hipStream_t stream)
{
    const float* query = (const float*)d_in[0];
    // d_in[1] = key (unused: reference's k projection is dead code)
    const float* value = (const float*)d_in[2];
    const float* Wq = (const float*)d_in[3];
    const float* bq = (const float*)d_in[4];
    // d_in[5], d_in[6] = Wk, bk (unused)
    const float* Wv = (const float*)d_in[7];
    const float* bv = (const float*)d_in[8];
    const float* Wo = (const float*)d_in[9];
    const float* bo = (const float*)d_in[10];
    const float* rpk = (const float*)d_in[11];
    const float* rpv = (const float*)d_in[12];
    float* out = (float*)d_out;

    char* ws = (char*)d_ws;
    const size_t MB = 1024 * 1024;
    _Float16* q_bhsd = (_Float16*)(ws);             // 8 MB: q proj (B,H,S,D)
    _Float16* v_t    = (_Float16*)(ws + 8 * MB);    // 8 MB: v proj (B,H,D,S)
    _Float16* q16    = (_Float16*)(ws + 16 * MB);   // 8 MB: query fp16
    _Float16* attn_o = (_Float16*)(ws + 16 * MB);   // aliases q16 (dead after gemm_qv)
    _Float16* v16    = (_Float16*)(ws + 24 * MB);   // 8 MB: value fp16
    _Float16* wq16   = (_Float16*)(ws + 32 * MB);   // 2 MB
    _Float16* wv16   = (_Float16*)(ws + 34 * MB);   // 2 MB
    _Float16* wo16   = (_Float16*)(ws + 36 * MB);   // 2 MB   (total 38 MB)

    cvt5_kernel<<<dim3(4096, 5), 256, 0, stream>>>(
        query, value, Wq, Wv, Wo, q16, v16, wq16, wv16, wo16,
        4096 * 1024, 4096 * 1024, 1024 * 1024, 1024 * 1024, 1024 * 1024);

    gemm_qv_kernel<<<dim3(8, 32, 2), 256, 0, stream>>>(
        q16, v16, wq16, wv16, bq, bv, q_bhsd, v_t);

    attn_kernel<<<dim3(16, 64), 256, 0, stream>>>(q_bhsd, v_t, rpk, rpv, attn_o);

    gemm_o_kernel<<<dim3(8, 32), 256, 0, stream>>>(attn_o, wo16, bo, out);
}

// Round 2
// 232.079 us; speedup vs baseline: 1.2963x; 1.2963x over previous
//
#include <hip/hip_runtime.h>

// B=4, S=1024, E=1024, H=16, D=64. All GEMMs are 4096x1024x1024 (A MxK row-major,
// W NxK row-major => C = A * W^T + bias).

typedef _Float16 v8h __attribute__((ext_vector_type(8)));
typedef _Float16 v4h __attribute__((ext_vector_type(4)));
typedef float    v4f __attribute__((ext_vector_type(4)));

#define MFMA_F16(A_, B_, C_) __builtin_amdgcn_mfma_f32_16x16x32_f16(A_, B_, C_, 0, 0, 0)

// async global->LDS, 16 B per lane; LDS dest = wave-uniform base + lane*16
__device__ __forceinline__ void async_copy16(const void* g, void* l) {
    __builtin_amdgcn_global_load_lds(
        (const __attribute__((address_space(1))) void*)g,
        (__attribute__((address_space(3))) void*)l, 16, 0, 0);
}

// ---------------- fp32 -> fp16 conversion (5 tensors, one launch) ----------------
__global__ __launch_bounds__(256) void cvt5_kernel(
    const float* __restrict__ s0, const float* __restrict__ s1,
    const float* __restrict__ s2, const float* __restrict__ s3,
    const float* __restrict__ s4,
    _Float16* __restrict__ d0, _Float16* __restrict__ d1,
    _Float16* __restrict__ d2, _Float16* __restrict__ d3,
    _Float16* __restrict__ d4,
    int n0, int n1, int n2, int n3, int n4)
{
    const float* s; _Float16* d; int n;
    switch (blockIdx.y) {
        case 0:  s = s0; d = d0; n = n0; break;
        case 1:  s = s1; d = d1; n = n1; break;
        case 2:  s = s2; d = d2; n = n2; break;
        case 3:  s = s3; d = d3; n = n3; break;
        default: s = s4; d = d4; n = n4; break;
    }
    int i = (blockIdx.x * 256 + threadIdx.x) * 4;
    if (i >= n) return;
    float4 f = *(const float4*)(s + i);
    v4h o = { (_Float16)f.x, (_Float16)f.y, (_Float16)f.z, (_Float16)f.w };
    *(v4h*)(d + i) = o;
}

// ---------------- shared GEMM core: C = A * W^T + bias ----------------
// 128x128 tile, BK=64, 256 threads (4 waves, 2x2). LDS rows of 64 halves, XOR
// swizzle: physical 8-half chunk pc holds logical chunk pc ^ (row&7). Staged via
// global_load_lds (16B/lane); compute-side ds_read_b128 conflict-free.
// mode 0: fp16 to (B,H,S,D); mode 1: fp16 transposed to (B,H,D,S); mode 2: fp32 (M,N).
__device__ __forceinline__ void gemm_core(const _Float16* __restrict__ A,
                                          const _Float16* __restrict__ W,
                                          const float* __restrict__ bias,
                                          int mode, void* __restrict__ outp)
{
    __shared__ __align__(16) _Float16 As[128 * 64];
    __shared__ __align__(16) _Float16 Bs[128 * 64];

    const int tid  = threadIdx.x;
    const int wave = tid >> 6, lane = tid & 63;
    const int quad = lane >> 4, n16 = lane & 15;
    const int wm = wave >> 1, wn = wave & 1;
    const int row0 = blockIdx.y * 128, col0 = blockIdx.x * 128;
    const int rL = lane >> 3, c8 = lane & 7;
    const int lcs = c8 ^ rL;              // logical chunk this lane stages (rL in 0..7)

    v4f acc[4][4] = {};

    for (int kb = 0; kb < 1024; kb += 64) {
        __syncthreads();
        #pragma unroll
        for (int p = 0; p < 4; p++) {
            int c = wave * 4 + p;         // 16 chunks of 8 rows each
            int row = c * 8 + rL;
            async_copy16(A + (size_t)(row0 + row) * 1024 + kb + lcs * 8, &As[c * 512]);
            async_copy16(W + (size_t)(col0 + row) * 1024 + kb + lcs * 8, &Bs[c * 512]);
        }
        __syncthreads();                  // compiler drains vmcnt before barrier
        #pragma unroll
        for (int ks = 0; ks < 64; ks += 32) {
            const int pc = ((ks >> 3) + quad) ^ (n16 & 7);
            v8h af[4], bf[4];
            #pragma unroll
            for (int i = 0; i < 4; i++)
                af[i] = *(const v8h*)(&As[(wm * 64 + i * 16 + n16) * 64 + pc * 8]);
            #pragma unroll
            for (int j = 0; j < 4; j++)
                bf[j] = *(const v8h*)(&Bs[(wn * 64 + j * 16 + n16) * 64 + pc * 8]);
            #pragma unroll
            for (int i = 0; i < 4; i++)
                #pragma unroll
                for (int j = 0; j < 4; j++)
                    acc[i][j] = MFMA_F16(af[i], bf[j], acc[i][j]);
        }
    }

    // C/D layout (verified gfx950): col = lane&15, row = (lane>>4)*4 + reg
    #pragma unroll
    for (int i = 0; i < 4; i++)
        #pragma unroll
        for (int j = 0; j < 4; j++)
            #pragma unroll
            for (int r = 0; r < 4; r++) {
                int row = row0 + wm * 64 + i * 16 + quad * 4 + r;
                int col = col0 + wn * 64 + j * 16 + n16;
                float v = acc[i][j][r] + bias[col];
                if (mode == 0) {
                    int b = row >> 10, s = row & 1023, h = col >> 6, d = col & 63;
                    ((_Float16*)outp)[(((size_t)(b * 16 + h)) * 1024 + s) * 64 + d] = (_Float16)v;
                } else if (mode == 1) {
                    int b = row >> 10, s = row & 1023, h = col >> 6, d = col & 63;
                    ((_Float16*)outp)[(((size_t)(b * 16 + h)) * 64 + d) * 1024 + s] = (_Float16)v;
                } else {
                    ((float*)outp)[(size_t)row * 1024 + col] = v;
                }
            }
}

__global__ __launch_bounds__(256) void gemm_qv_kernel(
    const _Float16* __restrict__ Aq, const _Float16* __restrict__ Av,
    const _Float16* __restrict__ Wq, const _Float16* __restrict__ Wv,
    const float* __restrict__ bq, const float* __restrict__ bv,
    _Float16* __restrict__ q_out, _Float16* __restrict__ v_out)
{
    int z = blockIdx.z;
    gemm_core(z ? Av : Aq, z ? Wv : Wq, z ? bv : bq, z ? 1 : 0,
              z ? (void*)v_out : (void*)q_out);
}

__global__ __launch_bounds__(256) void gemm_o_kernel(
    const _Float16* __restrict__ A, const _Float16* __restrict__ W,
    const float* __restrict__ bias, float* __restrict__ outp)
{
    gemm_core(A, W, bias, 2, (void*)outp);
}

// ---------------- fused attention (static-max softmax, K == Q) ----------------
// Block: 64 q-rows (4 waves x 16). grid = (S/64, B*H).
// p[q,k] = exp((dot(q_q,q_k) + rpk_dot[bucket]) / 8 - |q_q|^2/8); no running max:
// the static shift bounds p <= ~30 (fp16-safe), softmax normalization cancels it.
__global__ __launch_bounds__(256) void attn_kernel(
    const _Float16* __restrict__ qb,   // (B,H,S,D) fp16
    const _Float16* __restrict__ vt,   // (B,H,D,S) fp16 (transposed)
    const float* __restrict__ rpk, const float* __restrict__ rpv,  // (5,64) fp32
    _Float16* __restrict__ attn_o)     // (B*S, H*D) fp16
{
    const int bh = blockIdx.y;
    const int q0 = blockIdx.x * 64;
    const int tid = threadIdx.x;
    const int wave = tid >> 6, lane = tid & 63;
    const int quad = lane >> 4, n16 = lane & 15;
    const int qw = q0 + wave * 16;
    const _Float16* Qh = qb + (size_t)bh * 1024 * 64;
    const _Float16* Vh = vt + (size_t)bh * 64 * 1024;

    __shared__ __align__(16) _Float16 Ks[64 * 64];
    __shared__ __align__(16) _Float16 Vs[64 * 64];
    __shared__ __align__(16) _Float16 Ps[4][16 * 64];
    __shared__ float rqs[4][16][6];

    // rc[m][t] = (dot(q_m, rpk[t]) - |q_m|^2) * 0.125  (static-max folded in)
    {
        int m = lane >> 2, seg = lane & 3;
        const _Float16* qrow = Qh + (size_t)(qw + m) * 64 + seg * 16;
        v8h qa = *(const v8h*)(qrow);
        v8h qc = *(const v8h*)(qrow + 8);
        float qd[16];
        #pragma unroll
        for (int x = 0; x < 8; x++) { qd[x] = (float)qa[x]; qd[8 + x] = (float)qc[x]; }
        float qq = 0.f;
        #pragma unroll
        for (int x = 0; x < 16; x++) qq += qd[x] * qd[x];
        qq += __shfl_xor(qq, 1);
        qq += __shfl_xor(qq, 2);
        #pragma unroll
        for (int t = 0; t < 5; t++) {
            float s = 0.f;
            #pragma unroll
            for (int x = 0; x < 16; x++) s += qd[x] * rpk[t * 64 + seg * 16 + x];
            s += __shfl_xor(s, 1);
            s += __shfl_xor(s, 2);
            if (seg == 0) rqs[wave][m][t] = (s - qq) * 0.125f;
        }
    }
    __syncthreads();

    float rc[4][5];
    #pragma unroll
    for (int r = 0; r < 4; r++)
        #pragma unroll
        for (int t = 0; t < 5; t++)
            rc[r][t] = rqs[wave][quad * 4 + r][t];

    // Q A-fragments: A[m=lane&15][k=quad*8+j]
    v8h aq0 = *(const v8h*)(Qh + (size_t)(qw + n16) * 64 + quad * 8);
    v8h aq1 = *(const v8h*)(Qh + (size_t)(qw + n16) * 64 + 32 + quad * 8);

    float lrow[4] = {}, blo[4] = {}, bm1[4] = {}, bc0[4] = {}, bp1[4] = {};
    v4f O[4] = {};

    const int rL = lane >> 3, c8 = lane & 7;
    const int lcs = c8 ^ rL;
    const int pphys0 = quad ^ (n16 & 7);        // logical chunks {quad, quad+4}
    const int pphys1 = (quad + 4) ^ (n16 & 7);

    for (int kb = 0; kb < 1024; kb += 64) {
        __syncthreads();
        #pragma unroll
        for (int p = 0; p < 2; p++) {
            int c = wave * 2 + p;               // 8 chunks of 8 rows each
            int row = c * 8 + rL;
            async_copy16(Qh + (size_t)(kb + row) * 64 + lcs * 8, &Ks[c * 512]);
            async_copy16(Vh + (size_t)row * 1024 + kb + lcs * 8, &Vs[c * 512]);
        }
        __syncthreads();

        float pp4[4][4];
        #pragma unroll
        for (int t = 0; t < 4; t++) {
            v8h bk0 = *(const v8h*)(&Ks[(t * 16 + n16) * 64 + pphys0 * 8]);
            v8h bk1 = *(const v8h*)(&Ks[(t * 16 + n16) * 64 + pphys1 * 8]);
            v4f s = {0.f, 0.f, 0.f, 0.f};
            s = MFMA_F16(aq0, bk0, s);
            s = MFMA_F16(aq1, bk1, s);
            const int dq = qw - (kb + t * 16);  // wave-uniform
            if (dq >= 32) {                     // whole tile: diff >= 2 (bucket lo)
                #pragma unroll
                for (int r = 0; r < 4; r++) {
                    float p = __expf(fmaf(s[r], 0.125f, rc[r][4]));
                    pp4[t][r] = p; lrow[r] += p; blo[r] += p;
                }
            } else if (dq <= -32) {             // whole tile: diff <= -2 (bucket hi, derived)
                #pragma unroll
                for (int r = 0; r < 4; r++) {
                    float p = __expf(fmaf(s[r], 0.125f, rc[r][0]));
                    pp4[t][r] = p; lrow[r] += p;
                }
            } else {                            // near-diagonal: full predication
                #pragma unroll
                for (int r = 0; r < 4; r++) {
                    int diff = dq + quad * 4 + r - n16;
                    float rv = diff >= 2  ? rc[r][4]
                             : diff == 1  ? rc[r][3]
                             : diff == 0  ? rc[r][2]
                             : diff == -1 ? rc[r][1]
                                          : rc[r][0];
                    float p = __expf(fmaf(s[r], 0.125f, rv));
                    pp4[t][r] = p; lrow[r] += p;
                    if (diff >= 2)       blo[r] += p;
                    else if (diff == 1)  bm1[r] += p;
                    else if (diff == 0)  bc0[r] += p;
                    else if (diff == -1) bp1[r] += p;
                }
            }
        }

        // P: C-layout -> LDS (swizzled) -> A-layout; same-wave DS ops are in-order
        #pragma unroll
        for (int t = 0; t < 4; t++)
            #pragma unroll
            for (int r = 0; r < 4; r++) {
                int row = quad * 4 + r, pcol = t * 16 + n16;
                int pc = (pcol >> 3) ^ (row & 7);
                Ps[wave][row * 64 + pc * 8 + (pcol & 7)] = (_Float16)pp4[t][r];
            }

        v8h pf0 = *(const v8h*)(&Ps[wave][n16 * 64 + pphys0 * 8]);
        v8h pf1 = *(const v8h*)(&Ps[wave][n16 * 64 + pphys1 * 8]);
        #pragma unroll
        for (int dt = 0; dt < 4; dt++) {
            v8h v0 = *(const v8h*)(&Vs[(dt * 16 + n16) * 64 + pphys0 * 8]);
            v8h v1 = *(const v8h*)(&Vs[(dt * 16 + n16) * 64 + pphys1 * 8]);
            O[dt] = MFMA_F16(pf0, v0, O[dt]);
            O[dt] = MFMA_F16(pf1, v1, O[dt]);
        }
    }

    // epilogue: reduce l + buckets across the 16 lanes, add rpv term
    #pragma unroll
    for (int r = 0; r < 4; r++) {
        float l = lrow[r], lo = blo[r], a1 = bm1[r], a0 = bc0[r], ap = bp1[r];
        #pragma unroll
        for (int off = 1; off < 16; off <<= 1) {
            l  += __shfl_xor(l,  off);
            lo += __shfl_xor(lo, off);
            a1 += __shfl_xor(a1, off);
            a0 += __shfl_xor(a0, off);
            ap += __shfl_xor(ap, off);
        }
        float hi  = l - lo - a1 - a0 - ap;  // k >= q+2 bucket
        float inv = 1.0f / l;
        int qg = qw + quad * 4 + r;
        int brow = (bh >> 4) * 1024 + qg;   // b*S + q
        int hcol = (bh & 15) * 64;          // h*D
        #pragma unroll
        for (int dt = 0; dt < 4; dt++) {
            int d = dt * 16 + n16;
            float w2 = lo * rpv[4 * 64 + d] + a1 * rpv[3 * 64 + d] + a0 * rpv[2 * 64 + d]
                     + ap * rpv[1 * 64 + d] + hi * rpv[0 * 64 + d];
            float val = (O[dt][r] + w2) * inv;
            attn_o[(size_t)brow * 1024 + hcol + d] = (_Float16)val;
        }
    }
}

// ---------------- host launcher ----------------
extern "C" void kernel_launch(void* const* d_in, const int* in_sizes, int n_in,
                              void* d_out, int out_size, void* d_ws, size_t ws_size,
                              hipStream_t stream)
{
    const float* query = (const float*)d_in[0];
    // d_in[1] = key (unused: reference's k projection is dead code)
    const float* value = (const float*)d_in[2];
    const float* Wq = (const float*)d_in[3];
    const float* bq = (const float*)d_in[4];
    // d_in[5], d_in[6] = Wk, bk (unused)
    const float* Wv = (const float*)d_in[7];
    const float* bv = (const float*)d_in[8];
    const float* Wo = (const float*)d_in[9];
    const float* bo = (const float*)d_in[10];
    const float* rpk = (const float*)d_in[11];
    const float* rpv = (const float*)d_in[12];
    float* out = (float*)d_out;

    char* ws = (char*)d_ws;
    const size_t MB = 1024 * 1024;
    _Float16* q_bhsd = (_Float16*)(ws);             // 8 MB: q proj (B,H,S,D)
    _Float16* v_t    = (_Float16*)(ws + 8 * MB);    // 8 MB: v proj (B,H,D,S)
    _Float16* q16    = (_Float16*)(ws + 16 * MB);   // 8 MB: query fp16
    _Float16* attn_o = (_Float16*)(ws + 16 * MB);   // aliases q16 (dead after gemm_qv)
    _Float16* v16    = (_Float16*)(ws + 24 * MB);   // 8 MB: value fp16
    _Float16* wq16   = (_Float16*)(ws + 32 * MB);   // 2 MB
    _Float16* wv16   = (_Float16*)(ws + 34 * MB);   // 2 MB
    _Float16* wo16   = (_Float16*)(ws + 36 * MB);   // 2 MB   (total 38 MB)

    cvt5_kernel<<<dim3(4096, 5), 256, 0, stream>>>(
        query, value, Wq, Wv, Wo, q16, v16, wq16, wv16, wo16,
        4096 * 1024, 4096 * 1024, 1024 * 1024, 1024 * 1024, 1024 * 1024);

    gemm_qv_kernel<<<dim3(8, 32, 2), 256, 0, stream>>>(
        q16, v16, wq16, wv16, bq, bv, q_bhsd, v_t);

    attn_kernel<<<dim3(16, 64), 256, 0, stream>>>(q_bhsd, v_t, rpk, rpv, attn_o);

    gemm_o_kernel<<<dim3(8, 32), 256, 0, stream>>>(attn_o, wo16, bo, out);
}

// Round 3
// 203.445 us; speedup vs baseline: 1.4787x; 1.1407x over previous
//
#include <hip/hip_runtime.h>

// B=4, S=1024, E=1024, H=16, D=64. All GEMMs are 4096x1024x1024 (A MxK row-major,
// W NxK row-major => C = A * W^T + bias).

typedef _Float16 v8h __attribute__((ext_vector_type(8)));
typedef _Float16 v4h __attribute__((ext_vector_type(4)));
typedef float    v4f __attribute__((ext_vector_type(4)));

#define MFMA_F16(A_, B_, C_) __builtin_amdgcn_mfma_f32_16x16x32_f16(A_, B_, C_, 0, 0, 0)

__device__ __forceinline__ void async_copy16(const void* g, void* l) {
    __builtin_amdgcn_global_load_lds(
        (const __attribute__((address_space(1))) void*)g,
        (__attribute__((address_space(3))) void*)l, 16, 0, 0);
}

// ---------------- fp32 -> fp16 conversion (5 tensors, one launch) ----------------
__global__ __launch_bounds__(256) void cvt5_kernel(
    const float* __restrict__ s0, const float* __restrict__ s1,
    const float* __restrict__ s2, const float* __restrict__ s3,
    const float* __restrict__ s4,
    _Float16* __restrict__ d0, _Float16* __restrict__ d1,
    _Float16* __restrict__ d2, _Float16* __restrict__ d3,
    _Float16* __restrict__ d4,
    int n0, int n1, int n2, int n3, int n4)
{
    const float* s; _Float16* d; int n;
    switch (blockIdx.y) {
        case 0:  s = s0; d = d0; n = n0; break;
        case 1:  s = s1; d = d1; n = n1; break;
        case 2:  s = s2; d = d2; n = n2; break;
        case 3:  s = s3; d = d3; n = n3; break;
        default: s = s4; d = d4; n = n4; break;
    }
    int i = (blockIdx.x * 256 + threadIdx.x) * 4;
    if (i >= n) return;
    float4 f = *(const float4*)(s + i);
    v4h o = { (_Float16)f.x, (_Float16)f.y, (_Float16)f.z, (_Float16)f.w };
    *(v4h*)(d + i) = o;
}

// ---------------- shared GEMM core: C = A * W^T + bias ----------------
// TM x 128 tile, BK=64, 256 threads. XOR-swizzled LDS (16B chunk c of row r holds
// logical chunk c ^ (r&7)); staged via global_load_lds 16B/lane. Epilogue goes
// through per-wave 8KB LDS scratch so all global stores are coalesced 16B/lane.
// mode 0: fp16 (B,H,S,D); mode 1: fp16 transposed (B,H,D,S); mode 2: fp32 (M,N).
template<int TM>
__device__ __forceinline__ void gemm_core(const _Float16* __restrict__ A,
                                          const _Float16* __restrict__ W,
                                          const float* __restrict__ bias,
                                          int mode, void* __restrict__ outp)
{
    __shared__ __align__(16) _Float16 smem[2 * 128 * 64];   // As | Bs, 32 KB
    _Float16* As = smem;
    _Float16* Bs = smem + 128 * 64;

    const int tid  = threadIdx.x;
    const int wave = tid >> 6, lane = tid & 63;
    const int quad = lane >> 4, n16 = lane & 15;
    const int wm = (TM == 128) ? (wave >> 1) : 0;
    const int wn = (TM == 128) ? (wave & 1) : wave;
    const int WCOLS = (TM == 128) ? 64 : 32;
    const int NJ = WCOLS / 16;
    const int row0 = blockIdx.y * TM, col0 = blockIdx.x * 128;
    const int rL = lane >> 3, c8 = lane & 7;
    const int lcs = c8 ^ rL;

    v4f acc[4][4] = {};

    for (int kb = 0; kb < 1024; kb += 64) {
        __syncthreads();
        #pragma unroll
        for (int p = 0; p < TM / 32; p++) {
            int rg = wave * (TM / 32) + p;
            int row = rg * 8 + rL;
            async_copy16(A + (size_t)(row0 + row) * 1024 + kb + lcs * 8, &As[rg * 512]);
        }
        #pragma unroll
        for (int p = 0; p < 4; p++) {
            int rg = wave * 4 + p;
            int row = rg * 8 + rL;
            async_copy16(W + (size_t)(col0 + row) * 1024 + kb + lcs * 8, &Bs[rg * 512]);
        }
        __syncthreads();
        #pragma unroll
        for (int ks = 0; ks < 64; ks += 32) {
            const int pc = ((ks >> 3) + quad) ^ (n16 & 7);
            v8h af[4], bf[4];
            #pragma unroll
            for (int i = 0; i < 4; i++)
                af[i] = *(const v8h*)(&As[(wm * 64 + i * 16 + n16) * 64 + pc * 8]);
            #pragma unroll
            for (int j = 0; j < NJ; j++)
                bf[j] = *(const v8h*)(&Bs[(wn * WCOLS + j * 16 + n16) * 64 + pc * 8]);
            #pragma unroll
            for (int i = 0; i < 4; i++)
                #pragma unroll
                for (int j = 0; j < NJ; j++)
                    acc[i][j] = MFMA_F16(af[i], bf[j], acc[i][j]);
        }
    }

    __syncthreads();                       // staged tiles dead; reuse LDS as scratch
    char* scb = (char*)smem + wave * 8192; // per-wave 8 KB

    const int b     = (row0 + wm * 64) >> 10;
    const int srow0 = (row0 + wm * 64) & 1023;

    if (mode == 0) {                       // [s][d] scratch, coalesced (B,H,S,D) stores
        _Float16* sc = (_Float16*)scb;
        #pragma unroll
        for (int i = 0; i < 4; i++)
            #pragma unroll
            for (int j = 0; j < 4; j++)
                #pragma unroll
                for (int r = 0; r < 4; r++) {
                    int rowL = i * 16 + quad * 4 + r, colL = j * 16 + n16;
                    float v = acc[i][j][r] + bias[col0 + wn * 64 + colL];
                    sc[rowL * 64 + (((colL >> 3) ^ (rowL & 7)) << 3) + (colL & 7)] = (_Float16)v;
                }
        int h = (col0 + wn * 64) >> 6;
        #pragma unroll
        for (int it = 0; it < 8; it++) {
            int rowR = it * 8 + (lane >> 3), cR = lane & 7;
            v8h val = *(const v8h*)(&sc[rowR * 64 + ((cR ^ (rowR & 7)) << 3)]);
            *(v8h*)((_Float16*)outp +
                    (((size_t)(b * 16 + h) * 1024 + srow0 + rowR) << 6) + cR * 8) = val;
        }
    } else if (mode == 1) {                // [d][s] scratch, coalesced (B,H,D,S) stores
        _Float16* sc = (_Float16*)scb;
        #pragma unroll
        for (int i = 0; i < 4; i++)
            #pragma unroll
            for (int j = 0; j < 4; j++) {
                int colL = j * 16 + n16;
                int c16 = i * 2 + (quad >> 1);
                v4h pk;
                #pragma unroll
                for (int r = 0; r < 4; r++)
                    pk[r] = (_Float16)(acc[i][j][r] + bias[col0 + wn * 64 + colL]);
                *(v4h*)(&sc[colL * 64 + ((c16 ^ (colL & 7)) << 3) + (quad & 1) * 4]) = pk;
            }
        #pragma unroll
        for (int it = 0; it < 8; it++) {
            int dR = it * 8 + (lane >> 3), scn = lane & 7;
            v8h val = *(const v8h*)(&sc[dR * 64 + ((scn ^ (dR & 7)) << 3)]);
            int cg = col0 + wn * 64 + dR;
            int h = cg >> 6, dl = cg & 63;
            *(v8h*)((_Float16*)outp +
                    ((size_t)((b * 16 + h) * 64 + dl) << 10) + srow0 + scn * 8) = val;
        }
    } else {                               // mode 2 (TM=64): fp32 [m][n], wave tile 64x32
        float* sc = (float*)scb;
        #pragma unroll
        for (int i = 0; i < 4; i++)
            #pragma unroll
            for (int j = 0; j < 2; j++)
                #pragma unroll
                for (int r = 0; r < 4; r++) {
                    int rowL = i * 16 + quad * 4 + r, colL = j * 16 + n16;
                    sc[rowL * 32 + (((colL >> 2) ^ (rowL & 7)) << 2) + (colL & 3)] =
                        acc[i][j][r] + bias[col0 + wn * 32 + colL];
                }
        #pragma unroll
        for (int it = 0; it < 8; it++) {
            int rowR = it * 8 + (lane >> 3), cR = lane & 7;
            v4f val = *(const v4f*)(&sc[rowR * 32 + ((cR ^ (rowR & 7)) << 2)]);
            *(v4f*)((float*)outp + (size_t)(row0 + rowR) * 1024 + col0 + wn * 32 + cR * 4) = val;
        }
    }
}

__global__ __launch_bounds__(256) void gemm_qv_kernel(
    const _Float16* __restrict__ Aq, const _Float16* __restrict__ Av,
    const _Float16* __restrict__ Wq, const _Float16* __restrict__ Wv,
    const float* __restrict__ bq, const float* __restrict__ bv,
    _Float16* __restrict__ q_out, _Float16* __restrict__ v_out)
{
    int z = blockIdx.z;
    gemm_core<128>(z ? Av : Aq, z ? Wv : Wq, z ? bv : bq, z ? 1 : 0,
                   z ? (void*)v_out : (void*)q_out);
}

__global__ __launch_bounds__(256) void gemm_o_kernel(
    const _Float16* __restrict__ A, const _Float16* __restrict__ W,
    const float* __restrict__ bias, float* __restrict__ outp)
{
    gemm_core<64>(A, W, bias, 2, (void*)outp);
}

// ---------------- fused attention (S^T form, static-max softmax, K == Q) --------
// Block: 64 q-rows (4 waves x 16). 1-D grid: bh = blk&63 (XCD-local), qtile = blk>>6.
// S^T = MFMA(K-frag, Q-frag): each lane owns ONE q-row (q = qw + n16) and 4
// k-consecutive scores -> per-lane bucket scalars, b64 P-pack, O^T epilogue.
__global__ __launch_bounds__(256) void attn_kernel(
    const _Float16* __restrict__ qb,   // (B,H,S,D) fp16
    const _Float16* __restrict__ vt,   // (B,H,D,S) fp16 (transposed)
    const float* __restrict__ rpk, const float* __restrict__ rpv,  // (5,64) fp32
    _Float16* __restrict__ attn_o)     // (B*S, H*D) fp16
{
    const int blk = blockIdx.x;
    const int bh = blk & 63;
    const int q0 = (blk >> 6) * 64;
    const int tid = threadIdx.x;
    const int wave = tid >> 6, lane = tid & 63;
    const int quad = lane >> 4, n16 = lane & 15;
    const int qw = q0 + wave * 16;
    const _Float16* Qh = qb + (size_t)bh * 1024 * 64;
    const _Float16* Vh = vt + (size_t)bh * 64 * 1024;

    __shared__ __align__(16) _Float16 Ks[64 * 64];
    __shared__ __align__(16) _Float16 Vs[64 * 64];
    __shared__ __align__(16) _Float16 Ps[4][16 * 64];
    __shared__ float rqs[4][16][5];

    // rc[t] = (dot(q_row, rpk[t]) - |q_row|^2) * 0.125 for this lane's own q-row
    {
        int m = lane >> 2, seg = lane & 3;
        const _Float16* qrow = Qh + (size_t)(qw + m) * 64 + seg * 16;
        v8h qa = *(const v8h*)(qrow);
        v8h qc = *(const v8h*)(qrow + 8);
        float qd[16];
        #pragma unroll
        for (int x = 0; x < 8; x++) { qd[x] = (float)qa[x]; qd[8 + x] = (float)qc[x]; }
        float qq = 0.f;
        #pragma unroll
        for (int x = 0; x < 16; x++) qq += qd[x] * qd[x];
        qq += __shfl_xor(qq, 1);
        qq += __shfl_xor(qq, 2);
        #pragma unroll
        for (int t = 0; t < 5; t++) {
            float s = 0.f;
            #pragma unroll
            for (int x = 0; x < 16; x++) s += qd[x] * rpk[t * 64 + seg * 16 + x];
            s += __shfl_xor(s, 1);
            s += __shfl_xor(s, 2);
            if (seg == 0) rqs[wave][m][t] = (s - qq) * 0.125f;
        }
    }
    __syncthreads();

    float rc[5];
    #pragma unroll
    for (int t = 0; t < 5; t++) rc[t] = rqs[wave][n16][t];

    // Q fragment (B-operand): B[n=q=lane&15][k=quad*8+j]
    v8h aq0 = *(const v8h*)(Qh + (size_t)(qw + n16) * 64 + quad * 8);
    v8h aq1 = *(const v8h*)(Qh + (size_t)(qw + n16) * 64 + 32 + quad * 8);

    // bucket sums for this lane's q-row; index matches rpk/rpv table row:
    // 4: diff>=2, 3: diff==1, 2: diff==0, 1: diff==-1, 0: diff<=-2
    float bkt[5] = {0.f, 0.f, 0.f, 0.f, 0.f};
    v4f O[4] = {};

    const int rL = lane >> 3, c8 = lane & 7;
    const int lcs = c8 ^ rL;
    const int pphys0 = quad ^ (n16 & 7);
    const int pphys1 = (quad + 4) ^ (n16 & 7);

    for (int kb = 0; kb < 1024; kb += 64) {
        __syncthreads();
        #pragma unroll
        for (int p = 0; p < 2; p++) {
            int c = wave * 2 + p;
            int row = c * 8 + rL;
            async_copy16(Qh + (size_t)(kb + row) * 64 + lcs * 8, &Ks[c * 512]);
            async_copy16(Vh + (size_t)row * 1024 + kb + lcs * 8, &Vs[c * 512]);
        }
        __syncthreads();

        #pragma unroll
        for (int t = 0; t < 4; t++) {
            v8h ak0 = *(const v8h*)(&Ks[(t * 16 + n16) * 64 + pphys0 * 8]);
            v8h ak1 = *(const v8h*)(&Ks[(t * 16 + n16) * 64 + pphys1 * 8]);
            v4f s = {0.f, 0.f, 0.f, 0.f};
            s = MFMA_F16(ak0, aq0, s);    // S^T: row (quad*4+r) = k-local, col (n16) = q
            s = MFMA_F16(ak1, aq1, s);
            const int dqt = qw - kb - t * 16;      // wave-uniform
            float pv[4];
            if (dqt >= 32) {                       // whole tile diff >= 2
                #pragma unroll
                for (int r = 0; r < 4; r++) {
                    float p = __expf(fmaf(s[r], 0.125f, rc[4]));
                    pv[r] = p; bkt[4] += p;
                }
            } else if (dqt <= -32) {               // whole tile diff <= -2
                #pragma unroll
                for (int r = 0; r < 4; r++) {
                    float p = __expf(fmaf(s[r], 0.125f, rc[0]));
                    pv[r] = p; bkt[0] += p;
                }
            } else {                               // near-diagonal tile
                #pragma unroll
                for (int r = 0; r < 4; r++) {
                    int diff = dqt + n16 - quad * 4 - r;
                    float rv = diff >= 2  ? rc[4]
                             : diff == 1  ? rc[3]
                             : diff == 0  ? rc[2]
                             : diff == -1 ? rc[1]
                                          : rc[0];
                    float p = __expf(fmaf(s[r], 0.125f, rv));
                    pv[r] = p;
                    bkt[4] += (diff >= 2)  ? p : 0.f;
                    bkt[3] += (diff == 1)  ? p : 0.f;
                    bkt[2] += (diff == 0)  ? p : 0.f;
                    bkt[1] += (diff == -1) ? p : 0.f;
                    bkt[0] += (diff <= -2) ? p : 0.f;
                }
            }
            // P pack: lane holds P[q=n16][k = t*16+quad*4 .. +3] -> one b64 write
            v4h pk = { (_Float16)pv[0], (_Float16)pv[1], (_Float16)pv[2], (_Float16)pv[3] };
            int c16 = t * 2 + (quad >> 1);
            *(v4h*)(&Ps[wave][n16 * 64 + ((c16 ^ (n16 & 7)) << 3) + (quad & 1) * 4]) = pk;
        }

        // P fragments (B-operand): B[n=q=n16][k=quad*8+j] -> single-chunk b128 reads
        v8h pf0 = *(const v8h*)(&Ps[wave][n16 * 64 + pphys0 * 8]);
        v8h pf1 = *(const v8h*)(&Ps[wave][n16 * 64 + pphys1 * 8]);
        #pragma unroll
        for (int dt = 0; dt < 4; dt++) {
            v8h av0 = *(const v8h*)(&Vs[(dt * 16 + n16) * 64 + pphys0 * 8]);
            v8h av1 = *(const v8h*)(&Vs[(dt * 16 + n16) * 64 + pphys1 * 8]);
            O[dt] = MFMA_F16(av0, pf0, O[dt]);    // O^T: row = d-local, col = q
            O[dt] = MFMA_F16(av1, pf1, O[dt]);
        }
    }

    // epilogue: reduce buckets across the 4 quads sharing this q-row
    #pragma unroll
    for (int t = 0; t < 5; t++) {
        bkt[t] += __shfl_xor(bkt[t], 16);
        bkt[t] += __shfl_xor(bkt[t], 32);
    }
    float l = bkt[0] + bkt[1] + bkt[2] + bkt[3] + bkt[4];
    float inv = 1.0f / l;
    int q = qw + n16;
    size_t orow = (size_t)((bh >> 4) * 1024 + q) * 1024 + (bh & 15) * 64;
    #pragma unroll
    for (int dt = 0; dt < 4; dt++) {
        int d0 = dt * 16 + quad * 4;
        v4h st;
        #pragma unroll
        for (int r = 0; r < 4; r++) {
            int d = d0 + r;
            float w2 = bkt[4] * rpv[4 * 64 + d] + bkt[3] * rpv[3 * 64 + d]
                     + bkt[2] * rpv[2 * 64 + d] + bkt[1] * rpv[1 * 64 + d]
                     + bkt[0] * rpv[0 * 64 + d];
            st[r] = (_Float16)((O[dt][r] + w2) * inv);
        }
        *(v4h*)(attn_o + orow + d0) = st;
    }
}

// ---------------- host launcher ----------------
extern "C" void kernel_launch(void* const* d_in, const int* in_sizes, int n_in,
                              void* d_out, int out_size, void* d_ws, size_t ws_size,
                              hipStream_t stream)
{
    const float* query = (const float*)d_in[0];
    // d_in[1] = key (unused: reference's k projection is dead code)
    const float* value = (const float*)d_in[2];
    const float* Wq = (const float*)d_in[3];
    const float* bq = (const float*)d_in[4];
    // d_in[5], d_in[6] = Wk, bk (unused)
    const float* Wv = (const float*)d_in[7];
    const float* bv = (const float*)d_in[8];
    const float* Wo = (const float*)d_in[9];
    const float* bo = (const float*)d_in[10];
    const float* rpk = (const float*)d_in[11];
    const float* rpv = (const float*)d_in[12];
    float* out = (float*)d_out;

    char* ws = (char*)d_ws;
    const size_t MB = 1024 * 1024;
    _Float16* q_bhsd = (_Float16*)(ws);             // 8 MB: q proj (B,H,S,D)
    _Float16* v_t    = (_Float16*)(ws + 8 * MB);    // 8 MB: v proj (B,H,D,S)
    _Float16* q16    = (_Float16*)(ws + 16 * MB);   // 8 MB: query fp16
    _Float16* attn_o = (_Float16*)(ws + 16 * MB);   // aliases q16 (dead after gemm_qv)
    _Float16* v16    = (_Float16*)(ws + 24 * MB);   // 8 MB: value fp16
    _Float16* wq16   = (_Float16*)(ws + 32 * MB);   // 2 MB
    _Float16* wv16   = (_Float16*)(ws + 34 * MB);   // 2 MB
    _Float16* wo16   = (_Float16*)(ws + 36 * MB);   // 2 MB   (total 38 MB)

    cvt5_kernel<<<dim3(4096, 5), 256, 0, stream>>>(
        query, value, Wq, Wv, Wo, q16, v16, wq16, wv16, wo16,
        4096 * 1024, 4096 * 1024, 1024 * 1024, 1024 * 1024, 1024 * 1024);

    gemm_qv_kernel<<<dim3(8, 32, 2), 256, 0, stream>>>(
        q16, v16, wq16, wv16, bq, bv, q_bhsd, v_t);

    attn_kernel<<<dim3(1024), 256, 0, stream>>>(q_bhsd, v_t, rpk, rpv, attn_o);

    gemm_o_kernel<<<dim3(8, 64), 256, 0, stream>>>(attn_o, wo16, bo, out);
}